// Round 3
// baseline (263337.524 us; speedup 1.0000x reference)
//
#include <hip/hip_runtime.h>
#include <math.h>

#define Bb 64
#define Ll 1024
#define Dd 512
#define G4 2048      // 4*D
#define PART_STRIDE 520

__device__ __forceinline__ float hsig(float v){ return fminf(fmaxf(0.2f*v + 0.5f, 0.f), 1.f); }

// ---------------- one-time: Wf = [Wc@Ww ; Uw]  (1536 x 2048), bf = bc@Ww + bw ----------------
__global__ __launch_bounds__(256) void wf_build(const float* __restrict__ Wc, const float* __restrict__ Ww,
                                                const float* __restrict__ Uw, float* __restrict__ Wf){
    int idx = blockIdx.x * 256 + threadIdx.x;   // k*2048 + j, k in [0,1536)
    int k = idx >> 11, j = idx & 2047;
    if (k < 2 * Dd){
        const float* wc = Wc + (size_t)k * Dd;
        float s = 0.f;
        for (int m = 0; m < Dd; ++m) s = fmaf(wc[m], Ww[(size_t)m * G4 + j], s);
        Wf[idx] = s;
    } else {
        Wf[idx] = Uw[(size_t)(k - 2 * Dd) * G4 + j];
    }
}

__global__ __launch_bounds__(256) void bf_build(const float* __restrict__ bc, const float* __restrict__ Ww,
                                                const float* __restrict__ bw, float* __restrict__ bf){
    int j = blockIdx.x * 256 + threadIdx.x;
    float s = bw[j];
    for (int m = 0; m < Dd; ++m) s = fmaf(bc[m], Ww[(size_t)m * G4 + j], s);
    bf[j] = s;
}

// ---------------- reader gate GEMM (prologue t=0 only) ----------------
__global__ __launch_bounds__(256) void gemm_reader(const float* __restrict__ xt, const float* __restrict__ h,
                                                   const float* __restrict__ Wr, const float* __restrict__ Ur,
                                                   float* __restrict__ part){
    __shared__ float inT[64][65];
    __shared__ float wT[64][32];
    const int bx = blockIdx.x;
    const int jt = bx & 63, ks = bx >> 6;
    const int j0 = jt * 32;
    const int k0 = ks * 256;
    const int tid = threadIdx.x;
    const int tj4 = (tid & 7) * 4;
    const int tb  = tid >> 3;              // 0..31
    float a00=0.f,a01=0.f,a02=0.f,a03=0.f;
    float a10=0.f,a11=0.f,a12=0.f,a13=0.f;
    for (int kk = 0; kk < 256; kk += 64){
        #pragma unroll
        for (int i = 0; i < 16; ++i){
            int idx = tid + i * 256;
            int b = idx >> 6, k = idx & 63;
            int kg = k0 + kk + k;
            inT[b][k] = (kg < Dd) ? xt[(size_t)b * (Ll * Dd) + kg] : h[b * Dd + kg - Dd];
        }
        #pragma unroll
        for (int i = 0; i < 8; ++i){
            int idx = tid + i * 256;
            int k = idx >> 5, j = idx & 31;
            int kg = k0 + kk + k;
            wT[k][j] = (kg < Dd) ? Wr[(size_t)kg * G4 + j0 + j] : Ur[(size_t)(kg - Dd) * G4 + j0 + j];
        }
        __syncthreads();
        #pragma unroll 8
        for (int k = 0; k < 64; ++k){
            float4 wv = *(const float4*)&wT[k][tj4];
            float i0 = inT[tb][k];
            float i1 = inT[tb + 32][k];
            a00 = fmaf(i0, wv.x, a00); a01 = fmaf(i0, wv.y, a01);
            a02 = fmaf(i0, wv.z, a02); a03 = fmaf(i0, wv.w, a03);
            a10 = fmaf(i1, wv.x, a10); a11 = fmaf(i1, wv.y, a11);
            a12 = fmaf(i1, wv.z, a12); a13 = fmaf(i1, wv.w, a13);
        }
        __syncthreads();
    }
    size_t o0 = (size_t)(ks * Bb + tb) * G4 + j0 + tj4;
    size_t o1 = (size_t)(ks * Bb + tb + 32) * G4 + j0 + tj4;
    *(float4*)&part[o0] = make_float4(a00, a01, a02, a03);
    *(float4*)&part[o1] = make_float4(a10, a11, a12, a13);
}

__global__ __launch_bounds__(256) void reader_pw(const float* __restrict__ part, const float* __restrict__ br,
                                                 float* __restrict__ h, float* __restrict__ c){
    int idx = blockIdx.x * 256 + threadIdx.x;      // b*512 + d
    int b = idx >> 9, d = idx & 511;
    float z[4];
    #pragma unroll
    for (int g = 0; g < 4; ++g){
        int j = g * Dd + d;
        float s = br[j];
        #pragma unroll
        for (int ks = 0; ks < 4; ++ks) s += part[(size_t)(ks * Bb + b) * G4 + j];
        z[g] = s;
    }
    float i = hsig(z[0]), f = hsig(z[1]), g2 = tanhf(z[2]), o = hsig(z[3]);
    float cn = fmaf(f, c[idx], i * g2);
    c[idx] = cn;
    h[idx] = o * tanhf(cn);
}

// ---------------- FUSED GEMM: blocks [0,256) = writer(t), [256,512) = reader(t+1) ----------------
__global__ __launch_bounds__(256) void gemm_both(const float* __restrict__ o, const float* __restrict__ mrt,
                                                 const float* __restrict__ hw, const float* __restrict__ Wf,
                                                 float* __restrict__ partW,
                                                 const float* __restrict__ xt1, const float* __restrict__ Wr,
                                                 const float* __restrict__ Ur, float* __restrict__ partR){
    __shared__ float inT[64][65];
    __shared__ float wT[64][32];
    const int bxg = blockIdx.x;
    const int writer = (bxg < 256) ? 1 : 0;
    const int bx = writer ? bxg : bxg - 256;
    const int jt = bx & 63, ks = bx >> 6;
    const int j0 = jt * 32;
    const int tid = threadIdx.x;
    const int tj4 = (tid & 7) * 4;
    const int tb  = tid >> 3;
    float a00=0.f,a01=0.f,a02=0.f,a03=0.f;
    float a10=0.f,a11=0.f,a12=0.f,a13=0.f;
    const int KC = writer ? 384 : 256;
    const int k0 = ks * KC;
    for (int kk = 0; kk < KC; kk += 64){
        #pragma unroll
        for (int i = 0; i < 16; ++i){
            int idx = tid + i * 256;
            int b = idx >> 6, k = idx & 63;
            int kg = k0 + kk + k;
            float v;
            if (writer){
                if (kg < Dd)           v = o[b * Dd + kg];
                else if (kg < 2 * Dd)  v = mrt[b * Dd + kg - Dd];
                else                   v = hw[b * Dd + kg - 2 * Dd];
            } else {
                v = (kg < Dd) ? xt1[(size_t)b * (Ll * Dd) + kg] : o[b * Dd + kg - Dd];
            }
            inT[b][k] = v;
        }
        #pragma unroll
        for (int i = 0; i < 8; ++i){
            int idx = tid + i * 256;
            int k = idx >> 5, j = idx & 31;
            int kg = k0 + kk + k;
            float v;
            if (writer) v = Wf[(size_t)kg * G4 + j0 + j];
            else        v = (kg < Dd) ? Wr[(size_t)kg * G4 + j0 + j] : Ur[(size_t)(kg - Dd) * G4 + j0 + j];
            wT[k][j] = v;
        }
        __syncthreads();
        #pragma unroll 8
        for (int k = 0; k < 64; ++k){
            float4 wv = *(const float4*)&wT[k][tj4];
            float i0 = inT[tb][k];
            float i1 = inT[tb + 32][k];
            a00 = fmaf(i0, wv.x, a00); a01 = fmaf(i0, wv.y, a01);
            a02 = fmaf(i0, wv.z, a02); a03 = fmaf(i0, wv.w, a03);
            a10 = fmaf(i1, wv.x, a10); a11 = fmaf(i1, wv.y, a11);
            a12 = fmaf(i1, wv.z, a12); a13 = fmaf(i1, wv.w, a13);
        }
        __syncthreads();
    }
    float* part = writer ? partW : partR;
    size_t o0 = (size_t)(ks * Bb + tb) * G4 + j0 + tj4;
    size_t o1 = (size_t)(ks * Bb + tb + 32) * G4 + j0 + tj4;
    *(float4*)&part[o0] = make_float4(a00, a01, a02, a03);
    *(float4*)&part[o1] = make_float4(a10, a11, a12, a13);
}

// ---------------- FUSED PW: blocks [0,128) = writer_pw(t), [128,256) = reader_pw(t+1) ----------------
__global__ __launch_bounds__(256) void pw_both(const float* __restrict__ partW, const float* __restrict__ bfv,
                                               float* __restrict__ hw, float* __restrict__ cw,
                                               float* __restrict__ out, int last,
                                               const float* __restrict__ partR, const float* __restrict__ br,
                                               float* __restrict__ h, float* __restrict__ c){
    const int bxg = blockIdx.x;
    const int writer = (bxg < 128) ? 1 : 0;
    const int idx = (writer ? bxg : bxg - 128) * 256 + threadIdx.x;
    const int b = idx >> 9, d = idx & 511;
    const float* part = writer ? partW : partR;
    const float* bias = writer ? bfv : br;
    float z[4];
    #pragma unroll
    for (int g = 0; g < 4; ++g){
        int j = g * Dd + d;
        float s = bias[j];
        #pragma unroll
        for (int ks = 0; ks < 4; ++ks) s += part[(size_t)(ks * Bb + b) * G4 + j];
        z[g] = s;
    }
    float i = hsig(z[0]), f = hsig(z[1]), g2 = tanhf(z[2]), o = hsig(z[3]);
    if (writer){
        float cn = fmaf(f, cw[idx], i * g2);
        cw[idx] = cn;
        float hn = o * tanhf(cn);
        hw[idx] = hn;
        if (last) out[idx] = hn;
    } else {
        float cn = fmaf(f, c[idx], i * g2);
        c[idx] = cn;
        h[idx] = o * tanhf(cn);
    }
}

// ---------------- MEGA fp32: update(t-1) + scores(t) + online-softmax read + fused finalize ----------------
// grid 1024 = 64 b x 16 lb, block 256 (4 waves). wave handles 16 rows; lane owns d0=4*lane, d1=256+4*lane.
// mode: 0 = t==0 (no update), 1 = t==1 (update, forced full write), 2 = t>=2 (update, skippable write)
__global__ __launch_bounds__(256) void mega_f(const float* __restrict__ memIn, float* __restrict__ memOut,
                                              const float* __restrict__ o, const float* __restrict__ hwv,
                                              float* __restrict__ scores, float* __restrict__ Mb,
                                              float* __restrict__ Sinv,
                                              float* __restrict__ part, float* __restrict__ mrt,
                                              int* __restrict__ cnt, int mode){
    const int bid = blockIdx.x;
    const int b = bid >> 4, lb = bid & 15;
    const int tid = threadIdx.x;
    const int lane = tid & 63;
    const int gw = lb * 4 + (tid >> 6);     // 0..63
    const int d0 = lane * 4, d1 = 256 + lane * 4;
    float4 oa = *(const float4*)(o + b * Dd + d0);
    float4 obv = *(const float4*)(o + b * Dd + d1);
    float4 ha = make_float4(0.f,0.f,0.f,0.f), hb = make_float4(0.f,0.f,0.f,0.f);
    float Mp = 0.f, Sip = 0.f;
    if (mode){
        ha = *(const float4*)(hwv + b * Dd + d0);
        hb = *(const float4*)(hwv + b * Dd + d1);
        Mp = Mb[b]; Sip = Sinv[b];
    }
    float m = -INFINITY, ssum = 0.f;
    float a0x=0.f,a0y=0.f,a0z=0.f,a0w=0.f, a1x=0.f,a1y=0.f,a1z=0.f,a1w=0.f;
    const int lbase = gw * 16;
    float* srow = scores + b * Ll;
    #pragma unroll 2
    for (int r = 0; r < 16; ++r){
        const int l = lbase + r;
        const size_t base = ((size_t)b * Ll + l) * Dd;
        float4 v0 = *(const float4*)(memIn + base + d0);
        float4 v1 = *(const float4*)(memIn + base + d1);
        if (mode){
            float zp = __expf(srow[l] - Mp) * Sip;
            float om = 1.f - zp;
            v0.x = fmaf(v0.x, om, ha.x * zp); v0.y = fmaf(v0.y, om, ha.y * zp);
            v0.z = fmaf(v0.z, om, ha.z * zp); v0.w = fmaf(v0.w, om, ha.w * zp);
            v1.x = fmaf(v1.x, om, hb.x * zp); v1.y = fmaf(v1.y, om, hb.y * zp);
            v1.z = fmaf(v1.z, om, hb.z * zp); v1.w = fmaf(v1.w, om, hb.w * zp);
            if (mode == 1 || zp > 1e-7f){       // row-uniform branch; skip negligible updates
                *(float4*)(memOut + base + d0) = v0;
                *(float4*)(memOut + base + d1) = v1;
            }
        }
        float s = v0.x*oa.x + v0.y*oa.y + v0.z*oa.z + v0.w*oa.w
                + v1.x*obv.x + v1.y*obv.y + v1.z*obv.z + v1.w*obv.w;
        #pragma unroll
        for (int off = 32; off; off >>= 1) s += __shfl_xor(s, off);
        if (lane == 0) srow[l] = s;
        float nm = fmaxf(m, s);
        float sc = __expf(m - nm);
        float wt = __expf(s - nm);
        ssum = fmaf(ssum, sc, wt);
        a0x = fmaf(a0x, sc, v0.x * wt); a0y = fmaf(a0y, sc, v0.y * wt);
        a0z = fmaf(a0z, sc, v0.z * wt); a0w = fmaf(a0w, sc, v0.w * wt);
        a1x = fmaf(a1x, sc, v1.x * wt); a1y = fmaf(a1y, sc, v1.y * wt);
        a1z = fmaf(a1z, sc, v1.z * wt); a1w = fmaf(a1w, sc, v1.w * wt);
        m = nm;
    }
    float* p = part + (size_t)(b * 64 + gw) * PART_STRIDE;
    *(float4*)(p + d0) = make_float4(a0x, a0y, a0z, a0w);
    *(float4*)(p + d1) = make_float4(a1x, a1y, a1z, a1w);
    if (lane == 0){ p[512] = m; p[513] = ssum; }

    // ---- last-block-per-b finalize (replaces small_a dispatch) ----
    __threadfence();
    __syncthreads();
    __shared__ int lastF;
    if (tid == 0){
        int old = __hip_atomic_fetch_add(&cnt[b], 1, __ATOMIC_ACQ_REL, __HIP_MEMORY_SCOPE_AGENT);
        lastF = (old == 15) ? 1 : 0;
    }
    __syncthreads();
    if (!lastF) return;
    __threadfence();
    if (tid == 0) __hip_atomic_store(&cnt[b], 0, __ATOMIC_RELAXED, __HIP_MEMORY_SCOPE_AGENT);
    __shared__ float ews[64];
    if (tid < 64){
        const float* pp = part + (size_t)(b * 64 + tid) * PART_STRIDE;
        float mw = pp[512], sw = pp[513];
        float M = mw;
        #pragma unroll
        for (int off = 32; off; off >>= 1) M = fmaxf(M, __shfl_xor(M, off));
        float e = __expf(mw - M);
        float Ssum = sw * e;
        #pragma unroll
        for (int off = 32; off; off >>= 1) Ssum += __shfl_xor(Ssum, off);
        float Si = 1.f / Ssum;
        ews[tid] = e * Si;
        if (tid == 0){ Mb[b] = M; Sinv[b] = Si; }
    }
    __syncthreads();
    for (int d = tid; d < Dd; d += 256){
        float s = 0.f;
        #pragma unroll 8
        for (int w2 = 0; w2 < 64; ++w2)
            s = fmaf(part[(size_t)(b * 64 + w2) * PART_STRIDE + d], ews[w2], s);
        mrt[b * Dd + d] = s;
    }
}

extern "C" void kernel_launch(void* const* d_in, const int* in_sizes, int n_in,
                              void* d_out, int out_size, void* d_ws, size_t ws_size,
                              hipStream_t stream) {
    (void)in_sizes; (void)n_in; (void)out_size;
    const float* x  = (const float*)d_in[0];
    const float* Wr = (const float*)d_in[1];
    const float* Ur = (const float*)d_in[2];
    const float* br = (const float*)d_in[3];
    const float* Ww = (const float*)d_in[4];
    const float* Uw = (const float*)d_in[5];
    const float* bw = (const float*)d_in[6];
    const float* Wc = (const float*)d_in[7];
    const float* bc = (const float*)d_in[8];
    float* out = (float*)d_out;

    float* w = (float*)d_ws;
    float* mem     = w; w += (size_t)Bb * Ll * Dd;        // 134 MB fp32
    float* scores  = w; w += (size_t)Bb * Ll;
    float* part_me = w; w += (size_t)Bb * 64 * PART_STRIDE;
    float* Mb      = w; w += 64;
    float* Sinv    = w; w += 64;
    float* mrt     = w; w += (size_t)Bb * Dd;
    float* h_r     = w; w += (size_t)Bb * Dd;     // states + cnt: contiguous memset region
    float* c_r     = w; w += (size_t)Bb * Dd;
    float* hw      = w; w += (size_t)Bb * Dd;
    float* cw      = w; w += (size_t)Bb * Dd;
    int*   cnt     = (int*)w; w += 64;
    float* partR   = w; w += (size_t)4 * Bb * G4;
    float* partW   = w; w += (size_t)4 * Bb * G4;
    float* Wf      = w; w += (size_t)1536 * G4;
    float* bf      = w; w += G4;
    size_t need = (size_t)(w - (float*)d_ws) * sizeof(float);
    if (ws_size < need) return;

    // zero LSTM states + finalize counters (contiguous)
    hipMemsetAsync(h_r, 0, (size_t)4 * Bb * Dd * sizeof(float) + 64 * sizeof(int), stream);
    wf_build<<<(1536 * G4) / 256, 256, 0, stream>>>(Wc, Ww, Uw, Wf);
    bf_build<<<G4 / 256, 256, 0, stream>>>(bc, Ww, bw, bf);

    // prologue: reader step 0
    gemm_reader<<<256, 256, 0, stream>>>(x, h_r, Wr, Ur, partR);
    reader_pw<<<128, 256, 0, stream>>>(partR, br, h_r, c_r);

    for (int t = 0; t < Ll; ++t){
        const float* mi = (t <= 1) ? x : mem;
        int mode = (t == 0) ? 0 : ((t == 1) ? 1 : 2);
        mega_f<<<1024, 256, 0, stream>>>(mi, mem, h_r, hw, scores, Mb, Sinv, part_me, mrt, cnt, mode);
        int tn = (t + 1 < Ll) ? t + 1 : t;   // last-step reader output is unused
        gemm_both<<<512, 256, 0, stream>>>(h_r, mrt, hw, Wf, partW,
                                           x + (size_t)tn * Dd, Wr, Ur, partR);
        pw_both<<<256, 256, 0, stream>>>(partW, bf, hw, cw, out, t == Ll - 1 ? 1 : 0,
                                         partR, br, h_r, c_r);
    }
}

// Round 4
// 174665.698 us; speedup vs baseline: 1.5077x; 1.5077x over previous
//
#include <hip/hip_runtime.h>
#include <math.h>

#define Bb 64
#define Ll 1024
#define Dd 512
#define G4 2048      // 4*D
#define PART_STRIDE 516   // 512 d + m + ssum, padded off 512-stride

__device__ __forceinline__ float hsig(float v){ return fminf(fmaxf(0.2f*v + 0.5f, 0.f), 1.f); }

// ---------------- one-time: Wf = [Wc@Ww ; Uw]  (1536 x 2048), bf = bc@Ww + bw ----------------
__global__ __launch_bounds__(256) void wf_build(const float* __restrict__ Wc, const float* __restrict__ Ww,
                                                const float* __restrict__ Uw, float* __restrict__ Wf){
    int idx = blockIdx.x * 256 + threadIdx.x;   // k*2048 + j, k in [0,1536)
    int k = idx >> 11, j = idx & 2047;
    if (k < 2 * Dd){
        const float* wc = Wc + (size_t)k * Dd;
        float s = 0.f;
        for (int m = 0; m < Dd; ++m) s = fmaf(wc[m], Ww[(size_t)m * G4 + j], s);
        Wf[idx] = s;
    } else {
        Wf[idx] = Uw[(size_t)(k - 2 * Dd) * G4 + j];
    }
}

__global__ __launch_bounds__(256) void bf_build(const float* __restrict__ bc, const float* __restrict__ Ww,
                                                const float* __restrict__ bw, float* __restrict__ bf){
    int j = blockIdx.x * 256 + threadIdx.x;
    float s = bw[j];
    for (int m = 0; m < Dd; ++m) s = fmaf(bc[m], Ww[(size_t)m * G4 + j], s);
    bf[j] = s;
}

// ---------------- reader gate GEMM (prologue t=0 only) ----------------
__global__ __launch_bounds__(256) void gemm_reader(const float* __restrict__ xt, const float* __restrict__ h,
                                                   const float* __restrict__ Wr, const float* __restrict__ Ur,
                                                   float* __restrict__ part){
    __shared__ float inT[64][65];
    __shared__ float wT[64][32];
    const int bx = blockIdx.x;
    const int jt = bx & 63, ks = bx >> 6;
    const int j0 = jt * 32;
    const int k0 = ks * 256;
    const int tid = threadIdx.x;
    const int tj4 = (tid & 7) * 4;
    const int tb  = tid >> 3;              // 0..31
    float a00=0.f,a01=0.f,a02=0.f,a03=0.f;
    float a10=0.f,a11=0.f,a12=0.f,a13=0.f;
    for (int kk = 0; kk < 256; kk += 64){
        #pragma unroll
        for (int i = 0; i < 16; ++i){
            int idx = tid + i * 256;
            int b = idx >> 6, k = idx & 63;
            int kg = k0 + kk + k;
            inT[b][k] = (kg < Dd) ? xt[(size_t)b * (Ll * Dd) + kg] : h[b * Dd + kg - Dd];
        }
        #pragma unroll
        for (int i = 0; i < 8; ++i){
            int idx = tid + i * 256;
            int k = idx >> 5, j = idx & 31;
            int kg = k0 + kk + k;
            wT[k][j] = (kg < Dd) ? Wr[(size_t)kg * G4 + j0 + j] : Ur[(size_t)(kg - Dd) * G4 + j0 + j];
        }
        __syncthreads();
        #pragma unroll 8
        for (int k = 0; k < 64; ++k){
            float4 wv = *(const float4*)&wT[k][tj4];
            float i0 = inT[tb][k];
            float i1 = inT[tb + 32][k];
            a00 = fmaf(i0, wv.x, a00); a01 = fmaf(i0, wv.y, a01);
            a02 = fmaf(i0, wv.z, a02); a03 = fmaf(i0, wv.w, a03);
            a10 = fmaf(i1, wv.x, a10); a11 = fmaf(i1, wv.y, a11);
            a12 = fmaf(i1, wv.z, a12); a13 = fmaf(i1, wv.w, a13);
        }
        __syncthreads();
    }
    size_t o0 = (size_t)(ks * Bb + tb) * G4 + j0 + tj4;
    size_t o1 = (size_t)(ks * Bb + tb + 32) * G4 + j0 + tj4;
    *(float4*)&part[o0] = make_float4(a00, a01, a02, a03);
    *(float4*)&part[o1] = make_float4(a10, a11, a12, a13);
}

__global__ __launch_bounds__(256) void reader_pw(const float* __restrict__ part, const float* __restrict__ br,
                                                 float* __restrict__ h, float* __restrict__ c){
    int idx = blockIdx.x * 256 + threadIdx.x;      // b*512 + d
    int b = idx >> 9, d = idx & 511;
    float z[4];
    #pragma unroll
    for (int g = 0; g < 4; ++g){
        int j = g * Dd + d;
        float s = br[j];
        #pragma unroll
        for (int ks = 0; ks < 4; ++ks) s += part[(size_t)(ks * Bb + b) * G4 + j];
        z[g] = s;
    }
    float i = hsig(z[0]), f = hsig(z[1]), g2 = tanhf(z[2]), o = hsig(z[3]);
    float cn = fmaf(f, c[idx], i * g2);
    c[idx] = cn;
    h[idx] = o * tanhf(cn);
}

// ---------------- FUSED GEMM: blocks [0,256) = writer(t), [256,512) = reader(t+1) ----------------
__global__ __launch_bounds__(256) void gemm_both(const float* __restrict__ o, const float* __restrict__ mrt,
                                                 const float* __restrict__ hw, const float* __restrict__ Wf,
                                                 float* __restrict__ partW,
                                                 const float* __restrict__ xt1, const float* __restrict__ Wr,
                                                 const float* __restrict__ Ur, float* __restrict__ partR){
    __shared__ float inT[64][65];
    __shared__ float wT[64][32];
    const int bxg = blockIdx.x;
    const int writer = (bxg < 256) ? 1 : 0;
    const int bx = writer ? bxg : bxg - 256;
    const int jt = bx & 63, ks = bx >> 6;
    const int j0 = jt * 32;
    const int tid = threadIdx.x;
    const int tj4 = (tid & 7) * 4;
    const int tb  = tid >> 3;
    float a00=0.f,a01=0.f,a02=0.f,a03=0.f;
    float a10=0.f,a11=0.f,a12=0.f,a13=0.f;
    const int KC = writer ? 384 : 256;
    const int k0 = ks * KC;
    for (int kk = 0; kk < KC; kk += 64){
        #pragma unroll
        for (int i = 0; i < 16; ++i){
            int idx = tid + i * 256;
            int b = idx >> 6, k = idx & 63;
            int kg = k0 + kk + k;
            float v;
            if (writer){
                if (kg < Dd)           v = o[b * Dd + kg];
                else if (kg < 2 * Dd)  v = mrt[b * Dd + kg - Dd];
                else                   v = hw[b * Dd + kg - 2 * Dd];
            } else {
                v = (kg < Dd) ? xt1[(size_t)b * (Ll * Dd) + kg] : o[b * Dd + kg - Dd];
            }
            inT[b][k] = v;
        }
        #pragma unroll
        for (int i = 0; i < 8; ++i){
            int idx = tid + i * 256;
            int k = idx >> 5, j = idx & 31;
            int kg = k0 + kk + k;
            float v;
            if (writer) v = Wf[(size_t)kg * G4 + j0 + j];
            else        v = (kg < Dd) ? Wr[(size_t)kg * G4 + j0 + j] : Ur[(size_t)(kg - Dd) * G4 + j0 + j];
            wT[k][j] = v;
        }
        __syncthreads();
        #pragma unroll 8
        for (int k = 0; k < 64; ++k){
            float4 wv = *(const float4*)&wT[k][tj4];
            float i0 = inT[tb][k];
            float i1 = inT[tb + 32][k];
            a00 = fmaf(i0, wv.x, a00); a01 = fmaf(i0, wv.y, a01);
            a02 = fmaf(i0, wv.z, a02); a03 = fmaf(i0, wv.w, a03);
            a10 = fmaf(i1, wv.x, a10); a11 = fmaf(i1, wv.y, a11);
            a12 = fmaf(i1, wv.z, a12); a13 = fmaf(i1, wv.w, a13);
        }
        __syncthreads();
    }
    float* part = writer ? partW : partR;
    size_t o0 = (size_t)(ks * Bb + tb) * G4 + j0 + tj4;
    size_t o1 = (size_t)(ks * Bb + tb + 32) * G4 + j0 + tj4;
    *(float4*)&part[o0] = make_float4(a00, a01, a02, a03);
    *(float4*)&part[o1] = make_float4(a10, a11, a12, a13);
}

// ---------------- FUSED PW: blocks [0,128) = writer_pw(t), [128,256) = reader_pw(t+1) ----------------
__global__ __launch_bounds__(256) void pw_both(const float* __restrict__ partW, const float* __restrict__ bfv,
                                               float* __restrict__ hw, float* __restrict__ cw,
                                               float* __restrict__ out, int last,
                                               const float* __restrict__ partR, const float* __restrict__ br,
                                               float* __restrict__ h, float* __restrict__ c){
    const int bxg = blockIdx.x;
    const int writer = (bxg < 128) ? 1 : 0;
    const int idx = (writer ? bxg : bxg - 128) * 256 + threadIdx.x;
    const int b = idx >> 9, d = idx & 511;
    const float* part = writer ? partW : partR;
    const float* bias = writer ? bfv : br;
    float z[4];
    #pragma unroll
    for (int g = 0; g < 4; ++g){
        int j = g * Dd + d;
        float s = bias[j];
        #pragma unroll
        for (int ks = 0; ks < 4; ++ks) s += part[(size_t)(ks * Bb + b) * G4 + j];
        z[g] = s;
    }
    float i = hsig(z[0]), f = hsig(z[1]), g2 = tanhf(z[2]), o = hsig(z[3]);
    if (writer){
        float cn = fmaf(f, cw[idx], i * g2);
        cw[idx] = cn;
        float hn = o * tanhf(cn);
        hw[idx] = hn;
        if (last) out[idx] = hn;
    } else {
        float cn = fmaf(f, c[idx], i * g2);
        c[idx] = cn;
        h[idx] = o * tanhf(cn);
    }
}

// ---------------- MEGA fp32: update(t-1) + scores(t) + online-softmax read partials ----------------
// grid 2048 = 64 b x 32 lb, block 256 (4 waves, 8 blocks/CU). Wave handles 8 rows; lane owns d0, d1.
// mode: 0 = t==0 (no update/write), 1 = t>=1 (update + full write)
__global__ __launch_bounds__(256, 8) void mega_f(const float* __restrict__ memIn, float* __restrict__ memOut,
                                                 const float* __restrict__ o, const float* __restrict__ hwv,
                                                 float* __restrict__ scores, const float* __restrict__ Mb,
                                                 const float* __restrict__ Sinv,
                                                 float* __restrict__ part, int mode){
    const int bid = blockIdx.x;
    const int b = bid >> 5, lb = bid & 31;
    const int tid = threadIdx.x;
    const int lane = tid & 63;
    const int gw = lb * 4 + (tid >> 6);     // 0..127
    const int d0 = lane * 4, d1 = 256 + lane * 4;
    float4 oa = *(const float4*)(o + b * Dd + d0);
    float4 obv = *(const float4*)(o + b * Dd + d1);
    float4 ha = make_float4(0.f,0.f,0.f,0.f), hb = make_float4(0.f,0.f,0.f,0.f);
    float Mp = 0.f, Sip = 0.f;
    if (mode){
        ha = *(const float4*)(hwv + b * Dd + d0);
        hb = *(const float4*)(hwv + b * Dd + d1);
        Mp = Mb[b]; Sip = Sinv[b];
    }
    float m = -INFINITY, ssum = 0.f;
    float a0x=0.f,a0y=0.f,a0z=0.f,a0w=0.f, a1x=0.f,a1y=0.f,a1z=0.f,a1w=0.f;
    const int lbase = gw * 8;
    float* srow = scores + b * Ll;
    size_t base = ((size_t)b * Ll + lbase) * Dd;
    // register prefetch pipeline: loads for row r+1 issue before row r's dependent chain
    float4 c0 = *(const float4*)(memIn + base + d0);
    float4 c1 = *(const float4*)(memIn + base + d1);
    #pragma unroll
    for (int r = 0; r < 8; ++r){
        const int l = lbase + r;
        float4 v0 = c0, v1 = c1;
        if (r < 7){
            c0 = *(const float4*)(memIn + base + Dd + d0);
            c1 = *(const float4*)(memIn + base + Dd + d1);
        }
        if (mode){
            float zp = __expf(srow[l] - Mp) * Sip;
            float om = 1.f - zp;
            v0.x = fmaf(v0.x, om, ha.x * zp); v0.y = fmaf(v0.y, om, ha.y * zp);
            v0.z = fmaf(v0.z, om, ha.z * zp); v0.w = fmaf(v0.w, om, ha.w * zp);
            v1.x = fmaf(v1.x, om, hb.x * zp); v1.y = fmaf(v1.y, om, hb.y * zp);
            v1.z = fmaf(v1.z, om, hb.z * zp); v1.w = fmaf(v1.w, om, hb.w * zp);
            *(float4*)(memOut + base + d0) = v0;
            *(float4*)(memOut + base + d1) = v1;
        }
        float s = v0.x*oa.x + v0.y*oa.y + v0.z*oa.z + v0.w*oa.w
                + v1.x*obv.x + v1.y*obv.y + v1.z*obv.z + v1.w*obv.w;
        #pragma unroll
        for (int off = 32; off; off >>= 1) s += __shfl_xor(s, off);
        if (lane == 0) srow[l] = s;
        float nm = fmaxf(m, s);
        float sc = __expf(m - nm);
        float wt = __expf(s - nm);
        ssum = fmaf(ssum, sc, wt);
        a0x = fmaf(a0x, sc, v0.x * wt); a0y = fmaf(a0y, sc, v0.y * wt);
        a0z = fmaf(a0z, sc, v0.z * wt); a0w = fmaf(a0w, sc, v0.w * wt);
        a1x = fmaf(a1x, sc, v1.x * wt); a1y = fmaf(a1y, sc, v1.y * wt);
        a1z = fmaf(a1z, sc, v1.z * wt); a1w = fmaf(a1w, sc, v1.w * wt);
        m = nm;
        base += Dd;
    }
    float* p = part + (size_t)(b * 128 + gw) * PART_STRIDE;
    *(float4*)(p + d0) = make_float4(a0x, a0y, a0z, a0w);
    *(float4*)(p + d1) = make_float4(a1x, a1y, a1z, a1w);
    if (lane == 0){ p[512] = m; p[513] = ssum; }
}

// ---------------- finalize: combine 128 wave partials per b -> m_rt, M, 1/S ----------------
// grid 256 = 64 b x 4 d-segments; M/S reduce duplicated per block (cheap).
__global__ __launch_bounds__(256) void small_a(const float* __restrict__ part, float* __restrict__ mrt,
                                               float* __restrict__ Mb, float* __restrict__ Sinv){
    const int b = blockIdx.x >> 2, dseg = blockIdx.x & 3;
    const int tid = threadIdx.x;
    __shared__ float red[4];
    __shared__ float ews[128];
    __shared__ float psum[256];
    float mw = -INFINITY, sw = 0.f;
    if (tid < 128){
        const float* pp = part + (size_t)(b * 128 + tid) * PART_STRIDE;
        mw = pp[512]; sw = pp[513];
    }
    float M = mw;
    #pragma unroll
    for (int off = 32; off; off >>= 1) M = fmaxf(M, __shfl_xor(M, off));
    if (tid < 128 && (tid & 63) == 0) red[tid >> 6] = M;
    __syncthreads();
    float Mg = fmaxf(red[0], red[1]);
    float e = (tid < 128) ? __expf(mw - Mg) : 0.f;
    float Sl = sw * e;
    #pragma unroll
    for (int off = 32; off; off >>= 1) Sl += __shfl_xor(Sl, off);
    if (tid < 128 && (tid & 63) == 0) red[2 + (tid >> 6)] = Sl;
    __syncthreads();
    float Si = 1.f / (red[2] + red[3]);
    if (tid < 128) ews[tid] = e * Si;
    if (dseg == 0 && tid == 0){ Mb[b] = Mg; Sinv[b] = Si; }
    __syncthreads();
    const int dl = tid & 127, half = tid >> 7;
    const int d = dseg * 128 + dl;
    float s = 0.f;
    const float* pb = part + (size_t)(b * 128 + half * 64) * PART_STRIDE + d;
    #pragma unroll 8
    for (int w2 = 0; w2 < 64; ++w2)
        s = fmaf(pb[(size_t)w2 * PART_STRIDE], ews[half * 64 + w2], s);
    psum[tid] = s;
    __syncthreads();
    if (half == 0) mrt[b * Dd + d] = psum[tid] + psum[tid + 128];
}

extern "C" void kernel_launch(void* const* d_in, const int* in_sizes, int n_in,
                              void* d_out, int out_size, void* d_ws, size_t ws_size,
                              hipStream_t stream) {
    (void)in_sizes; (void)n_in; (void)out_size;
    const float* x  = (const float*)d_in[0];
    const float* Wr = (const float*)d_in[1];
    const float* Ur = (const float*)d_in[2];
    const float* br = (const float*)d_in[3];
    const float* Ww = (const float*)d_in[4];
    const float* Uw = (const float*)d_in[5];
    const float* bw = (const float*)d_in[6];
    const float* Wc = (const float*)d_in[7];
    const float* bc = (const float*)d_in[8];
    float* out = (float*)d_out;

    float* w = (float*)d_ws;
    float* mem     = w; w += (size_t)Bb * Ll * Dd;            // 134 MB fp32
    float* scores  = w; w += (size_t)Bb * Ll;
    float* part_me = w; w += (size_t)Bb * 128 * PART_STRIDE;  // ~17 MB
    float* Mb      = w; w += 64;
    float* Sinv    = w; w += 64;
    float* mrt     = w; w += (size_t)Bb * Dd;
    float* h_r     = w; w += (size_t)Bb * Dd;     // states: contiguous memset region
    float* c_r     = w; w += (size_t)Bb * Dd;
    float* hw      = w; w += (size_t)Bb * Dd;
    float* cw      = w; w += (size_t)Bb * Dd;
    float* partR   = w; w += (size_t)4 * Bb * G4;
    float* partW   = w; w += (size_t)4 * Bb * G4;
    float* Wf      = w; w += (size_t)1536 * G4;
    float* bf      = w; w += G4;
    size_t need = (size_t)(w - (float*)d_ws) * sizeof(float);
    if (ws_size < need) return;

    hipMemsetAsync(h_r, 0, (size_t)4 * Bb * Dd * sizeof(float), stream);
    wf_build<<<(1536 * G4) / 256, 256, 0, stream>>>(Wc, Ww, Uw, Wf);
    bf_build<<<G4 / 256, 256, 0, stream>>>(bc, Ww, bw, bf);

    // prologue: reader step 0
    gemm_reader<<<256, 256, 0, stream>>>(x, h_r, Wr, Ur, partR);
    reader_pw<<<128, 256, 0, stream>>>(partR, br, h_r, c_r);

    for (int t = 0; t < Ll; ++t){
        const float* mi = (t <= 1) ? x : mem;   // mem becomes valid at t==1's full write
        mega_f<<<2048, 256, 0, stream>>>(mi, mem, h_r, hw, scores, Mb, Sinv, part_me, t == 0 ? 0 : 1);
        small_a<<<256, 256, 0, stream>>>(part_me, mrt, Mb, Sinv);
        int tn = (t + 1 < Ll) ? t + 1 : t;      // last-step reader output is unused
        gemm_both<<<512, 256, 0, stream>>>(h_r, mrt, hw, Wf, partW,
                                           x + (size_t)tn * Dd, Wr, Ur, partR);
        pw_both<<<256, 256, 0, stream>>>(partW, bf, hw, cw, out, t == Ll - 1 ? 1 : 0,
                                         partR, br, h_r, c_r);
    }
}

// Round 5
// 117552.710 us; speedup vs baseline: 2.2402x; 1.4859x over previous
//
#include <hip/hip_runtime.h>
#include <math.h>

#define Bb 64
#define Ll 1024
#define Dd 512
#define G4 2048      // 4*D
#define PART_STRIDE 520

__device__ __forceinline__ float hsig(float v){ return fminf(fmaxf(0.2f*v + 0.5f, 0.f), 1.f); }

// ---------------- one-time: Wf = [Wc@Ww ; Uw]  (1536 x 2048), bf = bc@Ww + bw ----------------
__global__ __launch_bounds__(256) void wf_build(const float* __restrict__ Wc, const float* __restrict__ Ww,
                                                const float* __restrict__ Uw, float* __restrict__ Wf){
    int idx = blockIdx.x * 256 + threadIdx.x;   // k*2048 + j, k in [0,1536)
    int k = idx >> 11, j = idx & 2047;
    if (k < 2 * Dd){
        const float* wc = Wc + (size_t)k * Dd;
        float s = 0.f;
        for (int m = 0; m < Dd; ++m) s = fmaf(wc[m], Ww[(size_t)m * G4 + j], s);
        Wf[idx] = s;
    } else {
        Wf[idx] = Uw[(size_t)(k - 2 * Dd) * G4 + j];
    }
}

__global__ __launch_bounds__(256) void bf_build(const float* __restrict__ bc, const float* __restrict__ Ww,
                                                const float* __restrict__ bw, float* __restrict__ bf){
    int j = blockIdx.x * 256 + threadIdx.x;
    float s = bw[j];
    for (int m = 0; m < Dd; ++m) s = fmaf(bc[m], Ww[(size_t)m * G4 + j], s);
    bf[j] = s;
}

// ---------------- reader gate GEMM (prologue t=0 only) ----------------
__global__ __launch_bounds__(256) void gemm_reader(const float* __restrict__ xt, const float* __restrict__ h,
                                                   const float* __restrict__ Wr, const float* __restrict__ Ur,
                                                   float* __restrict__ part){
    __shared__ float inT[64][65];
    __shared__ float wT[64][32];
    const int bx = blockIdx.x;
    const int jt = bx & 63, ks = bx >> 6;
    const int j0 = jt * 32;
    const int k0 = ks * 256;
    const int tid = threadIdx.x;
    const int tj4 = (tid & 7) * 4;
    const int tb  = tid >> 3;              // 0..31
    float a00=0.f,a01=0.f,a02=0.f,a03=0.f;
    float a10=0.f,a11=0.f,a12=0.f,a13=0.f;
    for (int kk = 0; kk < 256; kk += 64){
        #pragma unroll
        for (int i = 0; i < 16; ++i){
            int idx = tid + i * 256;
            int b = idx >> 6, k = idx & 63;
            int kg = k0 + kk + k;
            inT[b][k] = (kg < Dd) ? xt[(size_t)b * (Ll * Dd) + kg] : h[b * Dd + kg - Dd];
        }
        #pragma unroll
        for (int i = 0; i < 8; ++i){
            int idx = tid + i * 256;
            int k = idx >> 5, j = idx & 31;
            int kg = k0 + kk + k;
            wT[k][j] = (kg < Dd) ? Wr[(size_t)kg * G4 + j0 + j] : Ur[(size_t)(kg - Dd) * G4 + j0 + j];
        }
        __syncthreads();
        #pragma unroll 8
        for (int k = 0; k < 64; ++k){
            float4 wv = *(const float4*)&wT[k][tj4];
            float i0 = inT[tb][k];
            float i1 = inT[tb + 32][k];
            a00 = fmaf(i0, wv.x, a00); a01 = fmaf(i0, wv.y, a01);
            a02 = fmaf(i0, wv.z, a02); a03 = fmaf(i0, wv.w, a03);
            a10 = fmaf(i1, wv.x, a10); a11 = fmaf(i1, wv.y, a11);
            a12 = fmaf(i1, wv.z, a12); a13 = fmaf(i1, wv.w, a13);
        }
        __syncthreads();
    }
    size_t o0 = (size_t)(ks * Bb + tb) * G4 + j0 + tj4;
    size_t o1 = (size_t)(ks * Bb + tb + 32) * G4 + j0 + tj4;
    *(float4*)&part[o0] = make_float4(a00, a01, a02, a03);
    *(float4*)&part[o1] = make_float4(a10, a11, a12, a13);
}

__global__ __launch_bounds__(256) void reader_pw(const float* __restrict__ part, const float* __restrict__ br,
                                                 float* __restrict__ h, float* __restrict__ c){
    int idx = blockIdx.x * 256 + threadIdx.x;      // b*512 + d
    int b = idx >> 9, d = idx & 511;
    float z[4];
    #pragma unroll
    for (int g = 0; g < 4; ++g){
        int j = g * Dd + d;
        float s = br[j];
        #pragma unroll
        for (int ks = 0; ks < 4; ++ks) s += part[(size_t)(ks * Bb + b) * G4 + j];
        z[g] = s;
    }
    float i = hsig(z[0]), f = hsig(z[1]), g2 = tanhf(z[2]), o = hsig(z[3]);
    float cn = fmaf(f, c[idx], i * g2);
    c[idx] = cn;
    h[idx] = o * tanhf(cn);
}

// ---------------- FUSED GEMM: blocks [0,256) = writer(t), [256,512) = reader(t+1) ----------------
__global__ __launch_bounds__(256) void gemm_both(const float* __restrict__ o, const float* __restrict__ mrt,
                                                 const float* __restrict__ hw, const float* __restrict__ Wf,
                                                 float* __restrict__ partW,
                                                 const float* __restrict__ xt1, const float* __restrict__ Wr,
                                                 const float* __restrict__ Ur, float* __restrict__ partR){
    __shared__ float inT[64][65];
    __shared__ float wT[64][32];
    const int bxg = blockIdx.x;
    const int writer = (bxg < 256) ? 1 : 0;
    const int bx = writer ? bxg : bxg - 256;
    const int jt = bx & 63, ks = bx >> 6;
    const int j0 = jt * 32;
    const int tid = threadIdx.x;
    const int tj4 = (tid & 7) * 4;
    const int tb  = tid >> 3;
    float a00=0.f,a01=0.f,a02=0.f,a03=0.f;
    float a10=0.f,a11=0.f,a12=0.f,a13=0.f;
    const int KC = writer ? 384 : 256;
    const int k0 = ks * KC;
    for (int kk = 0; kk < KC; kk += 64){
        #pragma unroll
        for (int i = 0; i < 16; ++i){
            int idx = tid + i * 256;
            int b = idx >> 6, k = idx & 63;
            int kg = k0 + kk + k;
            float v;
            if (writer){
                if (kg < Dd)           v = o[b * Dd + kg];
                else if (kg < 2 * Dd)  v = mrt[b * Dd + kg - Dd];
                else                   v = hw[b * Dd + kg - 2 * Dd];
            } else {
                v = (kg < Dd) ? xt1[(size_t)b * (Ll * Dd) + kg] : o[b * Dd + kg - Dd];
            }
            inT[b][k] = v;
        }
        #pragma unroll
        for (int i = 0; i < 8; ++i){
            int idx = tid + i * 256;
            int k = idx >> 5, j = idx & 31;
            int kg = k0 + kk + k;
            float v;
            if (writer) v = Wf[(size_t)kg * G4 + j0 + j];
            else        v = (kg < Dd) ? Wr[(size_t)kg * G4 + j0 + j] : Ur[(size_t)(kg - Dd) * G4 + j0 + j];
            wT[k][j] = v;
        }
        __syncthreads();
        #pragma unroll 8
        for (int k = 0; k < 64; ++k){
            float4 wv = *(const float4*)&wT[k][tj4];
            float i0 = inT[tb][k];
            float i1 = inT[tb + 32][k];
            a00 = fmaf(i0, wv.x, a00); a01 = fmaf(i0, wv.y, a01);
            a02 = fmaf(i0, wv.z, a02); a03 = fmaf(i0, wv.w, a03);
            a10 = fmaf(i1, wv.x, a10); a11 = fmaf(i1, wv.y, a11);
            a12 = fmaf(i1, wv.z, a12); a13 = fmaf(i1, wv.w, a13);
        }
        __syncthreads();
    }
    float* part = writer ? partW : partR;
    size_t o0 = (size_t)(ks * Bb + tb) * G4 + j0 + tj4;
    size_t o1 = (size_t)(ks * Bb + tb + 32) * G4 + j0 + tj4;
    *(float4*)&part[o0] = make_float4(a00, a01, a02, a03);
    *(float4*)&part[o1] = make_float4(a10, a11, a12, a13);
}

// ---------------- FUSED PW: blocks [0,128) = writer_pw(t), [128,256) = reader_pw(t+1) ----------------
__global__ __launch_bounds__(256) void pw_both(const float* __restrict__ partW, const float* __restrict__ bfv,
                                               float* __restrict__ hw, float* __restrict__ cw,
                                               float* __restrict__ out, int last,
                                               const float* __restrict__ partR, const float* __restrict__ br,
                                               float* __restrict__ h, float* __restrict__ c){
    const int bxg = blockIdx.x;
    const int writer = (bxg < 128) ? 1 : 0;
    const int idx = (writer ? bxg : bxg - 128) * 256 + threadIdx.x;
    const int b = idx >> 9, d = idx & 511;
    const float* part = writer ? partW : partR;
    const float* bias = writer ? bfv : br;
    float z[4];
    #pragma unroll
    for (int g = 0; g < 4; ++g){
        int j = g * Dd + d;
        float s = bias[j];
        #pragma unroll
        for (int ks = 0; ks < 4; ++ks) s += part[(size_t)(ks * Bb + b) * G4 + j];
        z[g] = s;
    }
    float i = hsig(z[0]), f = hsig(z[1]), g2 = tanhf(z[2]), o = hsig(z[3]);
    if (writer){
        float cn = fmaf(f, cw[idx], i * g2);
        cw[idx] = cn;
        float hn = o * tanhf(cn);
        hw[idx] = hn;
        if (last) out[idx] = hn;
    } else {
        float cn = fmaf(f, c[idx], i * g2);
        c[idx] = cn;
        h[idx] = o * tanhf(cn);
    }
}

// ---------------- MEGA fp32: update(t-1) + scores(t) + online-softmax read partials ----------------
// grid 1024 = 64 b x 16 lb, block 256 (4 waves, exactly 4 blocks/CU). Wave owns 16 rows as TWO
// interleaved streams (r, r+8) with independent online-softmax state -> 2x memory-level parallelism.
// mode: 0 = t==0 (no update/write), 1 = t==1 (update + forced full write), 2 = t>=2 (skippable write)
__global__ __launch_bounds__(256, 4) void mega_f(const float* __restrict__ memIn, float* __restrict__ memOut,
                                                 const float* __restrict__ o, const float* __restrict__ hwv,
                                                 float* __restrict__ scores, const float* __restrict__ Mb,
                                                 const float* __restrict__ Sinv,
                                                 float* __restrict__ part, int mode){
    const int bid = blockIdx.x;
    const int b = bid >> 4, lb = bid & 15;
    const int tid = threadIdx.x;
    const int lane = tid & 63;
    const int gw = lb * 4 + (tid >> 6);     // 0..63
    const int d0 = lane * 4, d1 = 256 + lane * 4;
    float4 oa = *(const float4*)(o + b * Dd + d0);
    float4 obv = *(const float4*)(o + b * Dd + d1);
    float4 ha = make_float4(0.f,0.f,0.f,0.f), hb = make_float4(0.f,0.f,0.f,0.f);
    float Mp = 0.f, Sip = 0.f;
    if (mode){
        ha = *(const float4*)(hwv + b * Dd + d0);
        hb = *(const float4*)(hwv + b * Dd + d1);
        Mp = Mb[b]; Sip = Sinv[b];
    }
    // stream A: rows lbase..lbase+7 ; stream B: rows lbase+8..lbase+15
    float mA = -INFINITY, sAs = 0.f, mB = -INFINITY, sBs = 0.f;
    float A0x=0.f,A0y=0.f,A0z=0.f,A0w=0.f, A1x=0.f,A1y=0.f,A1z=0.f,A1w=0.f;
    float B0x=0.f,B0y=0.f,B0z=0.f,B0w=0.f, B1x=0.f,B1y=0.f,B1z=0.f,B1w=0.f;
    const int lbase = gw * 16;
    float* srow = scores + b * Ll;
    size_t baseA = ((size_t)b * Ll + lbase) * Dd;
    size_t baseB = baseA + (size_t)8 * Dd;
    #pragma unroll 2
    for (int r = 0; r < 8; ++r){
        float4 vA0 = *(const float4*)(memIn + baseA + d0);
        float4 vA1 = *(const float4*)(memIn + baseA + d1);
        float4 vB0 = *(const float4*)(memIn + baseB + d0);
        float4 vB1 = *(const float4*)(memIn + baseB + d1);
        if (mode){
            float zpA = __expf(srow[lbase + r] - Mp) * Sip;
            float zpB = __expf(srow[lbase + 8 + r] - Mp) * Sip;
            float omA = 1.f - zpA, omB = 1.f - zpB;
            vA0.x = fmaf(vA0.x, omA, ha.x * zpA); vA0.y = fmaf(vA0.y, omA, ha.y * zpA);
            vA0.z = fmaf(vA0.z, omA, ha.z * zpA); vA0.w = fmaf(vA0.w, omA, ha.w * zpA);
            vA1.x = fmaf(vA1.x, omA, hb.x * zpA); vA1.y = fmaf(vA1.y, omA, hb.y * zpA);
            vA1.z = fmaf(vA1.z, omA, hb.z * zpA); vA1.w = fmaf(vA1.w, omA, hb.w * zpA);
            vB0.x = fmaf(vB0.x, omB, ha.x * zpB); vB0.y = fmaf(vB0.y, omB, ha.y * zpB);
            vB0.z = fmaf(vB0.z, omB, ha.z * zpB); vB0.w = fmaf(vB0.w, omB, ha.w * zpB);
            vB1.x = fmaf(vB1.x, omB, hb.x * zpB); vB1.y = fmaf(vB1.y, omB, hb.y * zpB);
            vB1.z = fmaf(vB1.z, omB, hb.z * zpB); vB1.w = fmaf(vB1.w, omB, hb.w * zpB);
            if (mode == 1 || zpA > 1e-7f){
                *(float4*)(memOut + baseA + d0) = vA0;
                *(float4*)(memOut + baseA + d1) = vA1;
            }
            if (mode == 1 || zpB > 1e-7f){
                *(float4*)(memOut + baseB + d0) = vB0;
                *(float4*)(memOut + baseB + d1) = vB1;
            }
        }
        float sa = vA0.x*oa.x + vA0.y*oa.y + vA0.z*oa.z + vA0.w*oa.w
                 + vA1.x*obv.x + vA1.y*obv.y + vA1.z*obv.z + vA1.w*obv.w;
        float sb = vB0.x*oa.x + vB0.y*oa.y + vB0.z*oa.z + vB0.w*oa.w
                 + vB1.x*obv.x + vB1.y*obv.y + vB1.z*obv.z + vB1.w*obv.w;
        #pragma unroll
        for (int off = 32; off; off >>= 1){
            sa += __shfl_xor(sa, off);
            sb += __shfl_xor(sb, off);
        }
        if (lane == 0){ srow[lbase + r] = sa; srow[lbase + 8 + r] = sb; }
        float nmA = fmaxf(mA, sa);
        float scA = __expf(mA - nmA);
        float wtA = __expf(sa - nmA);
        sAs = fmaf(sAs, scA, wtA);
        A0x = fmaf(A0x, scA, vA0.x * wtA); A0y = fmaf(A0y, scA, vA0.y * wtA);
        A0z = fmaf(A0z, scA, vA0.z * wtA); A0w = fmaf(A0w, scA, vA0.w * wtA);
        A1x = fmaf(A1x, scA, vA1.x * wtA); A1y = fmaf(A1y, scA, vA1.y * wtA);
        A1z = fmaf(A1z, scA, vA1.z * wtA); A1w = fmaf(A1w, scA, vA1.w * wtA);
        mA = nmA;
        float nmB = fmaxf(mB, sb);
        float scB = __expf(mB - nmB);
        float wtB = __expf(sb - nmB);
        sBs = fmaf(sBs, scB, wtB);
        B0x = fmaf(B0x, scB, vB0.x * wtB); B0y = fmaf(B0y, scB, vB0.y * wtB);
        B0z = fmaf(B0z, scB, vB0.z * wtB); B0w = fmaf(B0w, scB, vB0.w * wtB);
        B1x = fmaf(B1x, scB, vB1.x * wtB); B1y = fmaf(B1y, scB, vB1.y * wtB);
        B1z = fmaf(B1z, scB, vB1.z * wtB); B1w = fmaf(B1w, scB, vB1.w * wtB);
        mB = nmB;
        baseA += Dd; baseB += Dd;
    }
    // merge streams A and B
    float M = fmaxf(mA, mB);
    float eA = __expf(mA - M), eB = __expf(mB - M);
    float ssum = sAs * eA + sBs * eB;
    float* p = part + (size_t)(b * 64 + gw) * PART_STRIDE;
    *(float4*)(p + d0) = make_float4(A0x * eA + B0x * eB, A0y * eA + B0y * eB,
                                     A0z * eA + B0z * eB, A0w * eA + B0w * eB);
    *(float4*)(p + d1) = make_float4(A1x * eA + B1x * eB, A1y * eA + B1y * eB,
                                     A1z * eA + B1z * eB, A1w * eA + B1w * eB);
    if (lane == 0){ p[512] = M; p[513] = ssum; }
}

// ---------------- finalize: combine 64 wave partials per b -> m_rt, M, 1/S ----------------
// grid 256 = 64 b x 4 d-segments; M/S reduce duplicated per block (cheap).
__global__ __launch_bounds__(256) void small_a(const float* __restrict__ part, float* __restrict__ mrt,
                                               float* __restrict__ Mb, float* __restrict__ Sinv){
    const int b = blockIdx.x >> 2, dseg = blockIdx.x & 3;
    const int tid = threadIdx.x;
    __shared__ float ews[64];
    __shared__ float psum[256];
    if (tid < 64){
        const float* pp = part + (size_t)(b * 64 + tid) * PART_STRIDE;
        float mw = pp[512], sw = pp[513];
        float M = mw;
        #pragma unroll
        for (int off = 32; off; off >>= 1) M = fmaxf(M, __shfl_xor(M, off));
        float e = __expf(mw - M);
        float Ssum = sw * e;
        #pragma unroll
        for (int off = 32; off; off >>= 1) Ssum += __shfl_xor(Ssum, off);
        float Si = 1.f / Ssum;
        ews[tid] = e * Si;
        if (dseg == 0 && tid == 0){ Mb[b] = M; Sinv[b] = Si; }
    }
    __syncthreads();
    const int dl = tid & 127, half = tid >> 7;
    const int d = dseg * 128 + dl;
    const float* pb = part + (size_t)(b * 64 + half * 32) * PART_STRIDE + d;
    float s = 0.f;
    #pragma unroll 8
    for (int w2 = 0; w2 < 32; ++w2)
        s = fmaf(pb[(size_t)w2 * PART_STRIDE], ews[half * 32 + w2], s);
    psum[tid] = s;
    __syncthreads();
    if (half == 0) mrt[b * Dd + d] = psum[tid] + psum[tid + 128];
}

extern "C" void kernel_launch(void* const* d_in, const int* in_sizes, int n_in,
                              void* d_out, int out_size, void* d_ws, size_t ws_size,
                              hipStream_t stream) {
    (void)in_sizes; (void)n_in; (void)out_size;
    const float* x  = (const float*)d_in[0];
    const float* Wr = (const float*)d_in[1];
    const float* Ur = (const float*)d_in[2];
    const float* br = (const float*)d_in[3];
    const float* Ww = (const float*)d_in[4];
    const float* Uw = (const float*)d_in[5];
    const float* bw = (const float*)d_in[6];
    const float* Wc = (const float*)d_in[7];
    const float* bc = (const float*)d_in[8];
    float* out = (float*)d_out;

    float* w = (float*)d_ws;
    float* mem     = w; w += (size_t)Bb * Ll * Dd;            // 134 MB fp32
    float* scores  = w; w += (size_t)Bb * Ll;
    float* part_me = w; w += (size_t)Bb * 64 * PART_STRIDE;   // ~8.5 MB
    float* Mb      = w; w += 64;
    float* Sinv    = w; w += 64;
    float* mrt     = w; w += (size_t)Bb * Dd;
    float* h_r     = w; w += (size_t)Bb * Dd;     // states: contiguous memset region
    float* c_r     = w; w += (size_t)Bb * Dd;
    float* hw      = w; w += (size_t)Bb * Dd;
    float* cw      = w; w += (size_t)Bb * Dd;
    float* partR   = w; w += (size_t)4 * Bb * G4;
    float* partW   = w; w += (size_t)4 * Bb * G4;
    float* Wf      = w; w += (size_t)1536 * G4;
    float* bf      = w; w += G4;
    size_t need = (size_t)(w - (float*)d_ws) * sizeof(float);
    if (ws_size < need) return;

    hipMemsetAsync(h_r, 0, (size_t)4 * Bb * Dd * sizeof(float), stream);
    wf_build<<<(1536 * G4) / 256, 256, 0, stream>>>(Wc, Ww, Uw, Wf);
    bf_build<<<G4 / 256, 256, 0, stream>>>(bc, Ww, bw, bf);

    // prologue: reader step 0
    gemm_reader<<<256, 256, 0, stream>>>(x, h_r, Wr, Ur, partR);
    reader_pw<<<128, 256, 0, stream>>>(partR, br, h_r, c_r);

    for (int t = 0; t < Ll; ++t){
        const float* mi = (t <= 1) ? x : mem;   // mem becomes fully valid at t==1's forced write
        int mode = (t == 0) ? 0 : ((t == 1) ? 1 : 2);
        mega_f<<<1024, 256, 0, stream>>>(mi, mem, h_r, hw, scores, Mb, Sinv, part_me, mode);
        small_a<<<256, 256, 0, stream>>>(part_me, mrt, Mb, Sinv);
        int tn = (t + 1 < Ll) ? t + 1 : t;      // last-step reader output is unused
        gemm_both<<<512, 256, 0, stream>>>(h_r, mrt, hw, Wf, partW,
                                           x + (size_t)tn * Dd, Wr, Ur, partR);
        pw_both<<<256, 256, 0, stream>>>(partW, bf, hw, cw, out, t == Ll - 1 ? 1 : 0,
                                         partR, br, h_r, c_r);
    }
}